// Round 5
// baseline (1324.804 us; speedup 1.0000x reference)
//
#include <hip/hip_runtime.h>
#include <math.h>

// Problem constants
#define BB   128
#define SS   1024
#define EH2  1024
#define DHD  512
#define AD   512
#define MTOT (BB*SS)   // 131072
#define KDIM 1024

// k2 tile: block = 256 thr (4 waves), tile 128 rows x 512 cols, BK=32
#define BM2   128
#define BK2   32
#define NSTEP (KDIM/BK2)   // 32

typedef __attribute__((ext_vector_type(8)))  short short8;
typedef __attribute__((ext_vector_type(16))) float f32x16;

static __device__ __forceinline__ unsigned short f2bf_rne(float x) {
    unsigned u = __float_as_uint(x);
    u += 0x7FFF + ((u >> 16) & 1);
    return (unsigned short)(u >> 16);
}

// ---------------------------------------------------------------------------
// k0: pack W_enc fp32 [K][A] -> Wt bf16 in MFMA-fragment order:
//   Wt[ks][kk2][ct][lane][j] = W[ks*32 + kk2*16 + (lane>>5)*8 + j][ct*32 + (lane&31)]
// ---------------------------------------------------------------------------
__global__ __launch_bounds__(256) void k0_wprep(
    const float* __restrict__ W, unsigned short* __restrict__ Wt)
{
    const int g     = blockIdx.x * 256 + threadIdx.x;  // 0..65535
    const int lane  = g & 63;
    const int ct    = (g >> 6) & 15;
    const int kk2   = (g >> 10) & 1;
    const int ks    = g >> 11;                          // 0..31
    const int col   = ct * 32 + (lane & 31);
    const int kbase = ks * 32 + kk2 * 16 + (lane >> 5) * 8;
    short8 out;
    #pragma unroll
    for (int j = 0; j < 8; ++j)
        out[j] = (short)f2bf_rne(W[(size_t)(kbase + j) * AD + col]);
    *(short8*)&Wt[(size_t)g * 8] = out;
}

// ---------------------------------------------------------------------------
// k1: dec_proj[b][a] = decoder_hidden[b] @ W_dec + b_attn   (bias folded)
// ---------------------------------------------------------------------------
__global__ __launch_bounds__(256) void k1_decproj(
    const float* __restrict__ dec,   // [B][DH]
    const float* __restrict__ Wdec,  // [DH][A]
    const float* __restrict__ bias,  // [A]
    float* __restrict__ dec_proj)    // [B][A]
{
    __shared__ float dls[DHD];
    const int b = blockIdx.x;
    const int t = threadIdx.x;
    for (int i = t; i < DHD; i += 256) dls[i] = dec[b * DHD + i];
    __syncthreads();
    float acc0 = bias[t];
    float acc1 = bias[t + 256];
    #pragma unroll 8
    for (int k = 0; k < DHD; ++k) {
        const float d = dls[k];
        acc0 += d * Wdec[(size_t)k * AD + t];
        acc1 += d * Wdec[(size_t)k * AD + t + 256];
    }
    dec_proj[b * AD + t]       = acc0;
    dec_proj[b * AD + t + 256] = acc1;
}

// ---------------------------------------------------------------------------
// k2: MFMA GEMM (split bf16 hi/lo) + fused tanh + v-dot -> scores[MTOT].
// 256 thr = 4 waves; wave tile 128 rows x 128 cols (acc[4][4] f32x16 = 256 AGPR).
// 1 wave/SIMD; everything pipelined in-wave:
//   B(ks+1) -> regs at step top (consumed next step, hidden under MFMA)
//   A(ks+2) -> regs (2-step window > HBM latency); convert+ds_write late.
// A in LDS fragment-linear double-buffer (zero conflicts). No vmcnt(0) drains.
// ---------------------------------------------------------------------------
__global__ __launch_bounds__(256, 1) void k2_gemm_score(
    const float* __restrict__ enc,          // [MTOT][K]
    const unsigned short* __restrict__ Wt,  // packed fragment order
    const float* __restrict__ dp,           // [B][A] (bias folded)
    const float* __restrict__ v,            // [A]
    float* __restrict__ scores)             // [MTOT]
{
    __shared__ unsigned short As[2][16][512];  // 32 KB: [buf][(hl*2+kk2)*4+mt][lane*8]
    __shared__ float dp_l[AD], v_l[AD];
    __shared__ float sred[4][BM2];

    const int t     = threadIdx.x;
    const int wn    = t >> 6;               // wave = n-quadrant (128 cols)
    const int lane  = t & 63;
    const int mbase = blockIdx.x * BM2;
    const int b     = blockIdx.x >> 3;      // 8 blocks per batch row

    dp_l[t]       = dp[b * AD + t];
    dp_l[t + 256] = dp[b * AD + t + 256];
    v_l[t]        = v[t];
    v_l[t + 256]  = v[t + 256];

    // A staging: thread -> (mt = wave, lane) slot; handles kk2 = 0 and 1.
    const int smt  = wn;                       // staging m-tile
    const int srow = smt * 32 + (lane & 31);
    const int so   = (lane >> 5) * 8;          // k sub-offset
    const float* aptr = enc + (size_t)(mbase + srow) * KDIM + so;

    // B fragment base (short8 units): ct = wn*4 + n
    const short8* bb8 = (const short8*)Wt + wn * 256 + lane;

    float4 pA0[4], pA1[4];    // A prefetch sets: [kk2*2 + half]
    short8 bcur[8], bnx[8];   // B regs: [kk2*4 + n]

#define LOADA(ks_, SET) do {                                                \
    const float* p_ = aptr + (ks_) * BK2;                                   \
    SET[0] = *(const float4*)(p_);                                          \
    SET[1] = *(const float4*)(p_ + 4);                                      \
    SET[2] = *(const float4*)(p_ + 16);                                     \
    SET[3] = *(const float4*)(p_ + 20);                                     \
} while (0)

#define LOADB(ks_, R) do {                                                  \
    _Pragma("unroll")                                                       \
    for (int q_ = 0; q_ < 8; ++q_)                                          \
        R[q_] = bb8[(ks_) * 2048 + (q_ >> 2) * 1024 + (q_ & 3) * 64];       \
} while (0)

#define CONVA(SET, buf_) do {                                               \
    _Pragma("unroll")                                                       \
    for (int kk2_ = 0; kk2_ < 2; ++kk2_) {                                  \
        const float4 xa_ = SET[kk2_ * 2];                                   \
        const float4 xb_ = SET[kk2_ * 2 + 1];                               \
        const float xs_[8] = {xa_.x, xa_.y, xa_.z, xa_.w,                   \
                              xb_.x, xb_.y, xb_.z, xb_.w};                  \
        short8 hi_, lo_;                                                    \
        _Pragma("unroll")                                                   \
        for (int j_ = 0; j_ < 8; ++j_) {                                    \
            const unsigned u_ = __float_as_uint(xs_[j_]);                   \
            hi_[j_] = (short)(u_ >> 16);                                    \
            lo_[j_] = (short)f2bf_rne(xs_[j_] - __uint_as_float(u_ & 0xFFFF0000u)); \
        }                                                                   \
        *(short8*)&As[buf_][kk2_ * 4 + smt][lane * 8]       = hi_;          \
        *(short8*)&As[buf_][(2 + kk2_) * 4 + smt][lane * 8] = lo_;          \
    }                                                                       \
} while (0)

#define MFMA_STEP(BUF, BREG) do {                                           \
    _Pragma("unroll")                                                       \
    for (int kk2_ = 0; kk2_ < 2; ++kk2_) {                                  \
        short8 aH_[4], aL_[4];                                              \
        _Pragma("unroll")                                                   \
        for (int mt_ = 0; mt_ < 4; ++mt_) {                                 \
            aH_[mt_] = *(const short8*)&As[BUF][kk2_ * 4 + mt_][lane * 8];  \
            aL_[mt_] = *(const short8*)&As[BUF][(2 + kk2_) * 4 + mt_][lane * 8]; \
        }                                                                   \
        _Pragma("unroll")                                                   \
        for (int mt_ = 0; mt_ < 4; ++mt_)                                   \
            _Pragma("unroll")                                               \
            for (int n_ = 0; n_ < 4; ++n_)                                  \
                acc[mt_][n_] = __builtin_amdgcn_mfma_f32_32x32x16_bf16(     \
                    aH_[mt_], BREG[kk2_ * 4 + n_], acc[mt_][n_], 0, 0, 0);  \
        _Pragma("unroll")                                                   \
        for (int mt_ = 0; mt_ < 4; ++mt_)                                   \
            _Pragma("unroll")                                               \
            for (int n_ = 0; n_ < 4; ++n_)                                  \
                acc[mt_][n_] = __builtin_amdgcn_mfma_f32_32x32x16_bf16(     \
                    aL_[mt_], BREG[kk2_ * 4 + n_], acc[mt_][n_], 0, 0, 0);  \
    }                                                                       \
} while (0)

    f32x16 acc[4][4];
    #pragma unroll
    for (int mt = 0; mt < 4; ++mt)
        #pragma unroll
        for (int n = 0; n < 4; ++n) acc[mt][n] = (f32x16)0.f;

    // prologue: A(0)->pA0, A(1)->pA1, B(0)->bcur; convert A(0) into As[0]
    LOADA(0, pA0);
    LOADA(1, pA1);
    LOADB(0, bcur);
    CONVA(pA0, 0);
    __syncthreads();

    for (int ks = 0; ks < NSTEP; ks += 2) {
        // STEP A: compute As[0] x bcur(=B ks); stage As[1]<-A(ks+1), bnx<-B(ks+1)
        if (ks + 1 < NSTEP) LOADB(ks + 1, bnx);
        if (ks + 2 < NSTEP) LOADA(ks + 2, pA0);
        MFMA_STEP(0, bcur);
        if (ks + 1 < NSTEP) CONVA(pA1, 1);
        __syncthreads();
        // STEP B: compute As[1] x bnx(=B ks+1); stage As[0]<-A(ks+2), bcur<-B(ks+2)
        if (ks + 2 < NSTEP) LOADB(ks + 2, bcur);
        if (ks + 3 < NSTEP) LOADA(ks + 3, pA1);
        MFMA_STEP(1, bnx);
        if (ks + 2 < NSTEP) CONVA(pA0, 0);
        __syncthreads();
    }
#undef LOADA
#undef LOADB
#undef CONVA
#undef MFMA_STEP

    // ---- epilogue: score[row] = sum_col v[col]*tanh(acc + dp[col])
    // 32x32 C/D: col = lane&31, row = 4*(lane>>5) + (r&3) + 8*(r>>2)
    const int c    = lane & 31;
    const int half = lane >> 5;
    float vv[4], dpv[4];
    #pragma unroll
    for (int n = 0; n < 4; ++n) {
        const int col = wn * 128 + n * 32 + c;
        vv[n]  = v_l[col];
        dpv[n] = dp_l[col];
    }
    #pragma unroll
    for (int mt = 0; mt < 4; ++mt) {
        float part[16];
        #pragma unroll
        for (int r = 0; r < 16; ++r) {
            float s = 0.f;
            #pragma unroll
            for (int n = 0; n < 4; ++n) {
                const float e  = acc[mt][n][r] + dpv[n];
                const float te = __expf(2.f * e);
                s += vv[n] * (1.f - __fdividef(2.f, te + 1.f));
            }
            part[r] = s;
        }
        #pragma unroll
        for (int off = 1; off < 32; off <<= 1)
            #pragma unroll
            for (int r = 0; r < 16; ++r)
                part[r] += __shfl_xor(part[r], off);
        if (c == 0) {
            #pragma unroll
            for (int r = 0; r < 16; ++r)
                sred[wn][mt * 32 + 4 * half + (r & 3) + 8 * (r >> 2)] = part[r];
        }
    }
    __syncthreads();
    if (t < BM2)
        scores[mbase + t] = sred[0][t] + sred[1][t] + sred[2][t] + sred[3][t];
}

// ---------------------------------------------------------------------------
// k3: mask + softmax over S
// ---------------------------------------------------------------------------
__global__ __launch_bounds__(256) void k3_softmax(
    const float* __restrict__ sc,    // [MTOT]
    const int*   __restrict__ mask,  // [B][S]
    float* __restrict__ wts)         // [B][S]
{
    const int b = blockIdx.x;
    const int t = threadIdx.x;
    float local[4];
    float mx = -3.0e38f;
    #pragma unroll
    for (int r = 0; r < 4; ++r) {
        const int s = r * 256 + t;
        float val = sc[b * SS + s];
        if (mask[b * SS + s] == 0) val = -1.0e10f;
        local[r] = val;
        mx = fmaxf(mx, val);
    }
    #pragma unroll
    for (int off = 1; off < 64; off <<= 1) mx = fmaxf(mx, __shfl_xor(mx, off));
    __shared__ float redm[4], reds[4];
    if ((t & 63) == 0) redm[t >> 6] = mx;
    __syncthreads();
    mx = fmaxf(fmaxf(redm[0], redm[1]), fmaxf(redm[2], redm[3]));

    float sum = 0.f;
    #pragma unroll
    for (int r = 0; r < 4; ++r) { local[r] = __expf(local[r] - mx); sum += local[r]; }
    #pragma unroll
    for (int off = 1; off < 64; off <<= 1) sum += __shfl_xor(sum, off);
    if ((t & 63) == 0) reds[t >> 6] = sum;
    __syncthreads();
    sum = reds[0] + reds[1] + reds[2] + reds[3];
    const float inv = 1.f / sum;
    #pragma unroll
    for (int r = 0; r < 4; ++r) wts[b * SS + r * 256 + t] = local[r] * inv;
}

// ---------------------------------------------------------------------------
// k4: context[b][e] = sum_s w[b][s] * enc[b][s][e]; 64-row chunks for
// more concurrent blocks (BW latency hiding).
// ---------------------------------------------------------------------------
#define SCHUNK 64
__global__ __launch_bounds__(256) void k4_context(
    const float* __restrict__ enc,   // [B][S][E]
    const float* __restrict__ wts,   // [B][S]
    float* __restrict__ ctx)         // [B][E], pre-zeroed
{
    const int b  = blockIdx.x;
    const int ch = blockIdx.y;
    const int e4 = threadIdx.x * 4;
    const float* encb = enc + (size_t)b * SS * EH2 + (size_t)ch * SCHUNK * EH2;
    const float* wb   = wts + b * SS + ch * SCHUNK;
    float4 acc = make_float4(0.f, 0.f, 0.f, 0.f);
    #pragma unroll 4
    for (int s = 0; s < SCHUNK; ++s) {
        const float w = wb[s];
        const float4 ev = *(const float4*)&encb[(size_t)s * EH2 + e4];
        acc.x = fmaf(w, ev.x, acc.x);
        acc.y = fmaf(w, ev.y, acc.y);
        acc.z = fmaf(w, ev.z, acc.z);
        acc.w = fmaf(w, ev.w, acc.w);
    }
    atomicAdd(&ctx[b * EH2 + e4 + 0], acc.x);
    atomicAdd(&ctx[b * EH2 + e4 + 1], acc.y);
    atomicAdd(&ctx[b * EH2 + e4 + 2], acc.z);
    atomicAdd(&ctx[b * EH2 + e4 + 3], acc.w);
}

// ---------------------------------------------------------------------------
extern "C" void kernel_launch(void* const* d_in, const int* in_sizes, int n_in,
                              void* d_out, int out_size, void* d_ws, size_t ws_size,
                              hipStream_t stream) {
    const float* enc    = (const float*)d_in[0];   // (B,S,EH2)
    const float* dec    = (const float*)d_in[1];   // (B,DH)
    const int*   mask   = (const int*)  d_in[2];   // (B,S)
    const float* W      = (const float*)d_in[3];   // (EH2+DH, A)
    const float* b_attn = (const float*)d_in[4];   // (A,)
    const float* v      = (const float*)d_in[5];   // (A,)

    float* out = (float*)d_out;
    float* ctx = out;                // B*EH2
    float* wts = out + BB * EH2;     // B*S

    unsigned short* Wt  = (unsigned short*)d_ws;                    // 1 MiB
    float* dec_proj     = (float*)((char*)d_ws + (1 << 20));        // 256 KiB
    float* scores       = dec_proj + BB * AD;                       // 512 KiB

    hipMemsetAsync(ctx, 0, (size_t)BB * EH2 * sizeof(float), stream);

    k0_wprep<<<256, 256, 0, stream>>>(W, Wt);

    k1_decproj<<<BB, 256, 0, stream>>>(dec, W + (size_t)EH2 * AD, b_attn, dec_proj);

    k2_gemm_score<<<MTOT / BM2, 256, 0, stream>>>(enc, Wt, dec_proj, v, scores);

    k3_softmax<<<BB, 256, 0, stream>>>(scores, mask, wts);

    dim3 g4(BB, SS / SCHUNK);        // (128, 16)
    k4_context<<<g4, 256, 0, stream>>>(enc, wts, ctx);
}

// Round 7
// 975.134 us; speedup vs baseline: 1.3586x; 1.3586x over previous
//
#include <hip/hip_runtime.h>
#include <math.h>

// Problem constants
#define BB   128
#define SS   1024
#define EH2  1024
#define DHD  512
#define AD   512
#define MTOT (BB*SS)   // 131072
#define KDIM 1024

// k2 tile: block = 256 thr (4 waves), tile 64 rows x 512 cols, BK=32
#define BM2   64
#define BK2   32
#define NSTEP (KDIM/BK2)   // 32

typedef __attribute__((ext_vector_type(8)))  short short8;
typedef __attribute__((ext_vector_type(16))) float f32x16;

static __device__ __forceinline__ unsigned short f2bf_rne(float x) {
    unsigned u = __float_as_uint(x);
    u += 0x7FFF + ((u >> 16) & 1);
    return (unsigned short)(u >> 16);
}

// ---------------------------------------------------------------------------
// k0: pack W_enc fp32 [K][A] -> Wt bf16 in MFMA-fragment order:
//   Wt[ks][kk2][ct][lane][j] = W[ks*32 + kk2*16 + (lane>>5)*8 + j][ct*32 + (lane&31)]
// ---------------------------------------------------------------------------
__global__ __launch_bounds__(256) void k0_wprep(
    const float* __restrict__ W, unsigned short* __restrict__ Wt)
{
    const int g     = blockIdx.x * 256 + threadIdx.x;  // 0..65535
    const int lane  = g & 63;
    const int ct    = (g >> 6) & 15;
    const int kk2   = (g >> 10) & 1;
    const int ks    = g >> 11;                          // 0..31
    const int col   = ct * 32 + (lane & 31);
    const int kbase = ks * 32 + kk2 * 16 + (lane >> 5) * 8;
    short8 out;
    #pragma unroll
    for (int j = 0; j < 8; ++j)
        out[j] = (short)f2bf_rne(W[(size_t)(kbase + j) * AD + col]);
    *(short8*)&Wt[(size_t)g * 8] = out;
}

// ---------------------------------------------------------------------------
// k1: dec_proj[b][a] = decoder_hidden[b] @ W_dec + b_attn   (bias folded)
// ---------------------------------------------------------------------------
__global__ __launch_bounds__(256) void k1_decproj(
    const float* __restrict__ dec,   // [B][DH]
    const float* __restrict__ Wdec,  // [DH][A]
    const float* __restrict__ bias,  // [A]
    float* __restrict__ dec_proj)    // [B][A]
{
    __shared__ float dls[DHD];
    const int b = blockIdx.x;
    const int t = threadIdx.x;
    for (int i = t; i < DHD; i += 256) dls[i] = dec[b * DHD + i];
    __syncthreads();
    float acc0 = bias[t];
    float acc1 = bias[t + 256];
    #pragma unroll 8
    for (int k = 0; k < DHD; ++k) {
        const float d = dls[k];
        acc0 += d * Wdec[(size_t)k * AD + t];
        acc1 += d * Wdec[(size_t)k * AD + t + 256];
    }
    dec_proj[b * AD + t]       = acc0;
    dec_proj[b * AD + t + 256] = acc1;
}

// ---------------------------------------------------------------------------
// k2: MFMA GEMM (split bf16 hi/lo) + fused tanh + v-dot -> scores[MTOT].
// 256 thr = 4 waves (n-split). Block tile 64 x 512, BK=32.
// B: fragment-ordered Wt, global->reg, HALF-STEP double-buffered (one 16-MFMA
//    cluster always covers the next B-half's L2 latency). No LDS for B.
// A: LDS double-buffer, fragment-linear (0 conflicts); reg-prefetch 1 step.
// 2 blocks/CU -> independent barrier groups overlap each other's drains.
// ---------------------------------------------------------------------------
#define AS_IDX(hl, kk2, mt) (((hl) * 2 + (kk2)) * 2 + (mt))

__global__ __launch_bounds__(256, 2) void k2_gemm_score(
    const float* __restrict__ enc,          // [MTOT][K]
    const unsigned short* __restrict__ Wt,  // packed fragment order
    const float* __restrict__ dp,           // [B][A] (bias folded)
    const float* __restrict__ v,            // [A]
    float* __restrict__ scores)             // [MTOT]
{
    __shared__ unsigned short As[2][8][512];   // 16 KB
    __shared__ float dp_l[AD], v_l[AD];
    __shared__ float sred[4][BM2];

    const int t     = threadIdx.x;
    const int wn    = t >> 6;               // wave = n-quadrant
    const int lane  = t & 63;
    const int mbase = blockIdx.x * BM2;
    const int b     = blockIdx.x >> 4;      // 16 blocks per batch row

    dp_l[t]       = dp[b * AD + t];
    dp_l[t + 256] = dp[b * AD + t + 256];
    v_l[t]        = v[t];
    v_l[t + 256]  = v[t + 256];

    // A staging task: (smt, skk2, lane) fragment slot, 8 fp32 each
    const int smt  = (t >> 6) & 1;
    const int skk2 = t >> 7;
    const int srow = smt * 32 + (lane & 31);
    const int skb  = skk2 * 16 + (lane >> 5) * 8;
    const float* aptr = enc + (size_t)(mbase + srow) * KDIM + skb;
    unsigned short* asH = &As[0][AS_IDX(0, skk2, smt)][lane * 8];
    unsigned short* asL = &As[0][AS_IDX(1, skk2, smt)][lane * 8];
    const int asStride = 8 * 512;   // halfwords per As buffer

    // B fragment base (short8 units): ct = wn*4 + n
    const short8* bb8 = (const short8*)Wt + wn * 256 + lane;

    short8 bA[4], bB[4];   // half-step B double buffer

#define LOADB_H(ks_, kk2_, R) do {                                          \
    _Pragma("unroll")                                                       \
    for (int n_ = 0; n_ < 4; ++n_)                                          \
        R[n_] = bb8[(ks_) * 2048 + (kk2_) * 1024 + n_ * 64];                \
} while (0)

#define CONV_WRITE_A(buf_, xa_, xb_) do {                                   \
    const float xs_[8] = {xa_.x, xa_.y, xa_.z, xa_.w, xb_.x, xb_.y, xb_.z, xb_.w}; \
    short8 hi_, lo_;                                                        \
    _Pragma("unroll")                                                       \
    for (int j_ = 0; j_ < 8; ++j_) {                                        \
        const unsigned u_ = __float_as_uint(xs_[j_]);                       \
        hi_[j_] = (short)(u_ >> 16);                                        \
        lo_[j_] = (short)f2bf_rne(xs_[j_] - __uint_as_float(u_ & 0xFFFF0000u)); \
    }                                                                       \
    *(short8*)(asH + (buf_) * asStride) = hi_;                              \
    *(short8*)(asL + (buf_) * asStride) = lo_;                              \
} while (0)

#define MFMA_H(BUF, KK2, R) do {                                            \
    const short8 aH0 = *(const short8*)&As[BUF][AS_IDX(0,KK2,0)][lane*8];   \
    const short8 aL0 = *(const short8*)&As[BUF][AS_IDX(1,KK2,0)][lane*8];   \
    const short8 aH1 = *(const short8*)&As[BUF][AS_IDX(0,KK2,1)][lane*8];   \
    const short8 aL1 = *(const short8*)&As[BUF][AS_IDX(1,KK2,1)][lane*8];   \
    __builtin_amdgcn_s_setprio(1);                                          \
    _Pragma("unroll")                                                       \
    for (int n_ = 0; n_ < 4; ++n_) {                                        \
        acc[0][n_] = __builtin_amdgcn_mfma_f32_32x32x16_bf16(aH0, R[n_], acc[0][n_], 0, 0, 0); \
        acc[0][n_] = __builtin_amdgcn_mfma_f32_32x32x16_bf16(aL0, R[n_], acc[0][n_], 0, 0, 0); \
        acc[1][n_] = __builtin_amdgcn_mfma_f32_32x32x16_bf16(aH1, R[n_], acc[1][n_], 0, 0, 0); \
        acc[1][n_] = __builtin_amdgcn_mfma_f32_32x32x16_bf16(aL1, R[n_], acc[1][n_], 0, 0, 0); \
    }                                                                       \
    __builtin_amdgcn_s_setprio(0);                                          \
} while (0)

    f32x16 acc[2][4];
    #pragma unroll
    for (int mi = 0; mi < 2; ++mi)
        #pragma unroll
        for (int n = 0; n < 4; ++n) acc[mi][n] = (f32x16)0.f;

    // prologue: stage A(0) into buf0; B(0,half0) into bA
    {
        const float4 xa = *(const float4*)(aptr);
        const float4 xb = *(const float4*)(aptr + 4);
        LOADB_H(0, 0, bA);
        CONV_WRITE_A(0, xa, xb);
    }
    __syncthreads();

// One K-step; reads As[BUF] + bA, stages As[BUF^1] + next bA. bB is scratch.
#define KSTEP(BUF, ks_)                                                      \
  {                                                                          \
    const bool pf = ((ks_) + 1 < NSTEP);                                     \
    LOADB_H((ks_), 1, bB);             /* current step, half 1 */            \
    float4 xa, xb;                                                           \
    if (pf) {                                                                \
        xa = *(const float4*)(aptr + ((ks_) + 1) * BK2);                     \
        xb = *(const float4*)(aptr + ((ks_) + 1) * BK2 + 4);                 \
    }                                                                        \
    MFMA_H(BUF, 0, bA);                /* covers bB + A-load latency */      \
    if (pf) LOADB_H((ks_) + 1, 0, bA); /* next step, half 0 */               \
    MFMA_H(BUF, 1, bB);                /* covers bA latency */               \
    if (pf) CONV_WRITE_A((BUF) ^ 1, xa, xb);                                 \
    __syncthreads();                                                         \
  }

    for (int ks = 0; ks < NSTEP; ks += 2) {
        KSTEP(0, ks);
        KSTEP(1, ks + 1);
    }
#undef KSTEP
#undef LOADB_H
#undef CONV_WRITE_A
#undef MFMA_H

    // ---- epilogue: score[row] = sum_col v[col]*tanh(acc + dp[col])
    // 32x32 C/D: col = lane&31, row = 4*(lane>>5) + (r&3) + 8*(r>>2)
    const int c    = lane & 31;
    const int half = lane >> 5;
    float vv[4], dpv[4];
    #pragma unroll
    for (int n = 0; n < 4; ++n) {
        const int col = wn * 128 + n * 32 + c;
        vv[n]  = v_l[col];
        dpv[n] = dp_l[col];
    }
    #pragma unroll
    for (int mi = 0; mi < 2; ++mi) {
        float part[16];
        #pragma unroll
        for (int r = 0; r < 16; ++r) {
            float s = 0.f;
            #pragma unroll
            for (int n = 0; n < 4; ++n) {
                const float e  = acc[mi][n][r] + dpv[n];
                const float te = __expf(2.f * e);
                s += vv[n] * (1.f - __fdividef(2.f, te + 1.f));
            }
            part[r] = s;
        }
        #pragma unroll
        for (int off = 1; off < 32; off <<= 1)
            #pragma unroll
            for (int r = 0; r < 16; ++r)
                part[r] += __shfl_xor(part[r], off);
        if (c == 0) {
            #pragma unroll
            for (int r = 0; r < 16; ++r)
                sred[wn][mi * 32 + 4 * half + (r & 3) + 8 * (r >> 2)] = part[r];
        }
    }
    __syncthreads();
    if (t < BM2)
        scores[mbase + t] = sred[0][t] + sred[1][t] + sred[2][t] + sred[3][t];
}

// ---------------------------------------------------------------------------
// k3: mask + softmax over S
// ---------------------------------------------------------------------------
__global__ __launch_bounds__(256) void k3_softmax(
    const float* __restrict__ sc,    // [MTOT]
    const int*   __restrict__ mask,  // [B][S]
    float* __restrict__ wts)         // [B][S]
{
    const int b = blockIdx.x;
    const int t = threadIdx.x;
    float local[4];
    float mx = -3.0e38f;
    #pragma unroll
    for (int r = 0; r < 4; ++r) {
        const int s = r * 256 + t;
        float val = sc[b * SS + s];
        if (mask[b * SS + s] == 0) val = -1.0e10f;
        local[r] = val;
        mx = fmaxf(mx, val);
    }
    #pragma unroll
    for (int off = 1; off < 64; off <<= 1) mx = fmaxf(mx, __shfl_xor(mx, off));
    __shared__ float redm[4], reds[4];
    if ((t & 63) == 0) redm[t >> 6] = mx;
    __syncthreads();
    mx = fmaxf(fmaxf(redm[0], redm[1]), fmaxf(redm[2], redm[3]));

    float sum = 0.f;
    #pragma unroll
    for (int r = 0; r < 4; ++r) { local[r] = __expf(local[r] - mx); sum += local[r]; }
    #pragma unroll
    for (int off = 1; off < 64; off <<= 1) sum += __shfl_xor(sum, off);
    if ((t & 63) == 0) reds[t >> 6] = sum;
    __syncthreads();
    sum = reds[0] + reds[1] + reds[2] + reds[3];
    const float inv = 1.f / sum;
    #pragma unroll
    for (int r = 0; r < 4; ++r) wts[b * SS + r * 256 + t] = local[r] * inv;
}

// ---------------------------------------------------------------------------
// k4 two-stage (no atomics): k4a writes per-chunk partials to ws,
// k4b reduces 8 partials -> ctx. Fallback atomic version if ws too small.
// ---------------------------------------------------------------------------
#define SCHUNK4 128
__global__ __launch_bounds__(256) void k4a_partial(
    const float* __restrict__ enc,   // [B][S][E]
    const float* __restrict__ wts,   // [B][S]
    float* __restrict__ part)        // [B][8][E]
{
    const int b  = blockIdx.x;
    const int ch = blockIdx.y;
    const int e4 = threadIdx.x * 4;
    const float* encb = enc + (size_t)b * SS * EH2 + (size_t)ch * SCHUNK4 * EH2;
    const float* wb   = wts + b * SS + ch * SCHUNK4;
    float4 acc = make_float4(0.f, 0.f, 0.f, 0.f);
    #pragma unroll 4
    for (int s = 0; s < SCHUNK4; ++s) {
        const float w = wb[s];
        const float4 ev = *(const float4*)&encb[(size_t)s * EH2 + e4];
        acc.x = fmaf(w, ev.x, acc.x);
        acc.y = fmaf(w, ev.y, acc.y);
        acc.z = fmaf(w, ev.z, acc.z);
        acc.w = fmaf(w, ev.w, acc.w);
    }
    *(float4*)&part[((size_t)b * 8 + ch) * EH2 + e4] = acc;
}

__global__ __launch_bounds__(256) void k4b_reduce(
    const float* __restrict__ part,  // [B][8][E]
    float* __restrict__ ctx)         // [B][E]
{
    const int b  = blockIdx.x;
    const int e4 = threadIdx.x * 4;
    float4 acc = make_float4(0.f, 0.f, 0.f, 0.f);
    #pragma unroll
    for (int ch = 0; ch < 8; ++ch) {
        const float4 p = *(const float4*)&part[((size_t)b * 8 + ch) * EH2 + e4];
        acc.x += p.x; acc.y += p.y; acc.z += p.z; acc.w += p.w;
    }
    *(float4*)&ctx[b * EH2 + e4] = acc;
}

__global__ __launch_bounds__(256) void k4_context_atomic(
    const float* __restrict__ enc, const float* __restrict__ wts,
    float* __restrict__ ctx)
{
    const int b  = blockIdx.x;
    const int ch = blockIdx.y;
    const int e4 = threadIdx.x * 4;
    const float* encb = enc + (size_t)b * SS * EH2 + (size_t)ch * SCHUNK4 * EH2;
    const float* wb   = wts + b * SS + ch * SCHUNK4;
    float4 acc = make_float4(0.f, 0.f, 0.f, 0.f);
    #pragma unroll 4
    for (int s = 0; s < SCHUNK4; ++s) {
        const float w = wb[s];
        const float4 ev = *(const float4*)&encb[(size_t)s * EH2 + e4];
        acc.x = fmaf(w, ev.x, acc.x);
        acc.y = fmaf(w, ev.y, acc.y);
        acc.z = fmaf(w, ev.z, acc.z);
        acc.w = fmaf(w, ev.w, acc.w);
    }
    atomicAdd(&ctx[b * EH2 + e4 + 0], acc.x);
    atomicAdd(&ctx[b * EH2 + e4 + 1], acc.y);
    atomicAdd(&ctx[b * EH2 + e4 + 2], acc.z);
    atomicAdd(&ctx[b * EH2 + e4 + 3], acc.w);
}

// ---------------------------------------------------------------------------
extern "C" void kernel_launch(void* const* d_in, const int* in_sizes, int n_in,
                              void* d_out, int out_size, void* d_ws, size_t ws_size,
                              hipStream_t stream) {
    const float* enc    = (const float*)d_in[0];   // (B,S,EH2)
    const float* dec    = (const float*)d_in[1];   // (B,DH)
    const int*   mask   = (const int*)  d_in[2];   // (B,S)
    const float* W      = (const float*)d_in[3];   // (EH2+DH, A)
    const float* b_attn = (const float*)d_in[4];   // (A,)
    const float* v      = (const float*)d_in[5];   // (A,)

    float* out = (float*)d_out;
    float* ctx = out;                // B*EH2
    float* wts = out + BB * EH2;     // B*S

    unsigned short* Wt  = (unsigned short*)d_ws;                    // 1 MiB
    float* dec_proj     = (float*)((char*)d_ws + (1 << 20));        // 256 KiB
    float* scores       = dec_proj + BB * AD;                       // 512 KiB
    float* part         = scores + MTOT;                            // 4 MiB
    const size_t ws_needed = (1u << 20) + (size_t)(BB * AD + MTOT + BB * 8 * EH2) * 4;

    k0_wprep<<<256, 256, 0, stream>>>(W, Wt);

    k1_decproj<<<BB, 256, 0, stream>>>(dec, W + (size_t)EH2 * AD, b_attn, dec_proj);

    k2_gemm_score<<<MTOT / BM2, 256, 0, stream>>>(enc, Wt, dec_proj, v, scores);

    k3_softmax<<<BB, 256, 0, stream>>>(scores, mask, wts);

    dim3 g4(BB, SS / SCHUNK4);       // (128, 8)
    if (ws_size >= ws_needed) {
        k4a_partial<<<g4, 256, 0, stream>>>(enc, wts, part);
        k4b_reduce<<<BB, 256, 0, stream>>>(part, ctx);
    } else {
        hipMemsetAsync(ctx, 0, (size_t)BB * EH2 * sizeof(float), stream);
        k4_context_atomic<<<g4, 256, 0, stream>>>(enc, wts, ctx);
    }
}